// Round 1
// baseline (105.998 us; speedup 1.0000x reference)
//
#include <hip/hip_runtime.h>
#include <hip/hip_bf16.h>

// ---------------------------------------------------------------------------
// ParticleQAEEncoder: 4 batched statevector sims.
//  - met: n=1 analytic
//  - ele/mu: n=4 (16 amps) per-thread in registers
//  - jet: n=10 (1024 amps) per-wave: 16 cplx/lane, shfl for wires 4..9
// Key identities:
//  * encoding == product state (alpha_k, beta_k per wire)
//  * "for t in trash: for l in latent: CNOT(t,l)" == flip all latent bits
//    iff parity(trash bits)   (controls/targets disjoint -> all commute)
//  * second CNOT block == flip all trash bits iff parity(latent bits)
//  * jet <Z_trash> == 4-bit Walsh-Hadamard over lane bits 0..3
// ---------------------------------------------------------------------------

struct cplx { float re, im; };

__device__ __forceinline__ cplx cmul(cplx a, cplx b) {
  cplx r; r.re = a.re*b.re - a.im*b.im; r.im = a.re*b.im + a.im*b.re; return r;
}
__device__ __forceinline__ cplx csel(int c, cplx a, cplx b) {
  cplx r; r.re = c ? a.re : b.re; r.im = c ? a.im : b.im; return r;
}
__device__ __forceinline__ cplx shflx(cplx v, int m) {
  cplx r; r.re = __shfl_xor(v.re, m, 64); r.im = __shfl_xor(v.im, m, 64); return r;
}

// |0>-column of RZ(phi)*RY(pt)*RX(eta)  (gates applied RX,RY,RZ order)
__device__ __forceinline__ void enc_col(float pt, float eta, float phi,
                                        cplx* A, cplx* Bq) {
  float cx = __cosf(0.5f*eta), sx = __sinf(0.5f*eta);
  float cy = __cosf(0.5f*pt),  sy = __sinf(0.5f*pt);
  float cz = __cosf(0.5f*phi), sz = __sinf(0.5f*phi);
  // after RX,RY: comp0 = u + i v, comp1 = p + i q
  float u = cy*cx, v = sy*sx;
  float p = sy*cx, q = -cy*sx;
  // RZ: comp0 *= (cz - i sz), comp1 *= (cz + i sz)
  A->re  = cz*u + sz*v;  A->im  = cz*v - sz*u;
  Bq->re = cz*p - sz*q;  Bq->im = cz*q + sz*p;
}

// ---------------- jet: n=10, latent wires 0..5 (idx bits 9..4),
// trash wires 6..9 (idx bits 3..0), depth 4 ----------------
__device__ void jet_sim(const float* __restrict__ xr, const float* __restrict__ jw,
                        float* __restrict__ out, int b, int lane, int jet_off) {
  cplx A[10], Bw[10];
  #pragma unroll
  for (int k = 0; k < 10; ++k)
    enc_col(xr[26+k], xr[36+k], xr[46+k], &A[k], &Bw[k]);

  // lane holds idx bits 0..5 (wires 9..4); reg r holds idx bits 6..9 (wires 3..0)
  cplx lf = csel((lane >> 5) & 1, Bw[4], A[4]);
  #pragma unroll
  for (int k = 5; k < 10; ++k)
    lf = cmul(lf, csel((lane >> (9-k)) & 1, Bw[k], A[k]));

  cplx st[16];
  #pragma unroll
  for (int r = 0; r < 16; ++r) {
    cplx f = lf;
    #pragma unroll
    for (int k = 0; k < 4; ++k)
      f = cmul(f, csel((r >> (3-k)) & 1, Bw[k], A[k]));
    st[r] = f;
  }

  const int p1 = __popc(lane & 15) & 1;   // parity of trash bits (lane bits 0..3)
  const int lp = __popc(lane >> 4) & 1;   // parity of latent lane bits (4,5)

  for (int d = 0; d < 4; ++d) {
    // P1: new[i] = old[i ^ 0x3F0] iff parity(i & 0xF)  -> lane^48, r^15
    #pragma unroll
    for (int r = 0; r < 8; ++r) {
      cplx v1 = st[r], v2 = st[r^15];
      cplx o1 = shflx(v2, 48);
      cplx o2 = shflx(v1, 48);
      st[r]    = csel(p1, o1, v1);
      st[r^15] = csel(p1, o2, v2);
    }
    // RY(weights[d*10+k]) on each wire
    float c[10], s[10];
    #pragma unroll
    for (int k = 0; k < 10; ++k) {
      float a = 0.5f * jw[d*10 + k];
      c[k] = __cosf(a); s[k] = __sinf(a);
    }
    // wires 0..3: register-pair updates (r-bit 3-k)
    #pragma unroll
    for (int k = 0; k < 4; ++k) {
      const int mr = 1 << (3-k);
      #pragma unroll
      for (int r = 0; r < 16; ++r) {
        if (!(r & mr)) {
          cplx a = st[r], bb = st[r|mr];
          st[r].re    = c[k]*a.re - s[k]*bb.re;
          st[r].im    = c[k]*a.im - s[k]*bb.im;
          st[r|mr].re = s[k]*a.re + c[k]*bb.re;
          st[r|mr].im = s[k]*a.im + c[k]*bb.im;
        }
      }
    }
    // wires 4..9: cross-lane (lane-bit 9-k)
    #pragma unroll
    for (int k = 4; k < 10; ++k) {
      const int lm = 1 << (9-k);
      const float sg = (lane & lm) ? s[k] : -s[k];
      #pragma unroll
      for (int r = 0; r < 16; ++r) {
        cplx o = shflx(st[r], lm);
        st[r].re = c[k]*st[r].re + sg*o.re;
        st[r].im = c[k]*st[r].im + sg*o.im;
      }
    }
    // P2: new[i] = old[i ^ 0xF] iff parity(i & 0x3F0)
    #pragma unroll
    for (int r = 0; r < 16; ++r) {
      cplx o = shflx(st[r], 15);
      const int p2 = (lp ^ (__popc(r) & 1)) & 1;
      st[r] = csel(p2, o, st[r]);
    }
  }

  // probabilities: trash bits are lane bits 3..0 only
  float pr = 0.f;
  #pragma unroll
  for (int r = 0; r < 16; ++r)
    pr += st[r].re*st[r].re + st[r].im*st[r].im;
  // sum over latent lane bits 4,5
  pr += __shfl_xor(pr, 16, 64);
  pr += __shfl_xor(pr, 32, 64);
  // Walsh-Hadamard over lane bits 0..3: lane m -> sum (-1)^{popc(l&m)} pr(l)
  float y = pr;
  #pragma unroll
  for (int j = 1; j <= 8; j <<= 1) {
    float aa = __shfl_xor(y, j, 64);
    y = (lane & j) ? (aa - y) : (y + aa);
  }
  // wire 6 -> bit3 -> lane 8; wire 7 -> lane 4; wire 8 -> lane 2; wire 9 -> lane 1
  if (lane == 8) out[jet_off + b*4 + 0] = y;
  if (lane == 4) out[jet_off + b*4 + 1] = y;
  if (lane == 2) out[jet_off + b*4 + 2] = y;
  if (lane == 1) out[jet_off + b*4 + 3] = y;
}

// ---------------- ele/mu: n=4, latent wires 0,1 (bits 3,2),
// trash wires 2,3 (bits 1,0), depth 1 ----------------
__device__ void sim4(const float* __restrict__ pt, const float* __restrict__ eta,
                     const float* __restrict__ phi, const float* __restrict__ w,
                     float* z_w2, float* z_w3) {
  cplx A[4], Bw[4];
  #pragma unroll
  for (int k = 0; k < 4; ++k)
    enc_col(pt[k], eta[k], phi[k], &A[k], &Bw[k]);

  cplx st[16];
  #pragma unroll
  for (int i = 0; i < 16; ++i) {
    cplx f = csel((i>>3)&1, Bw[0], A[0]);
    f = cmul(f, csel((i>>2)&1, Bw[1], A[1]));
    f = cmul(f, csel((i>>1)&1, Bw[2], A[2]));
    f = cmul(f, csel( i    &1, Bw[3], A[3]));
    st[i] = f;
  }
  // P1: i ^= 0xC iff parity(i&3): swap pairs (1,13),(2,14),(5,9),(6,10)
  cplx t;
  t = st[1]; st[1] = st[13]; st[13] = t;
  t = st[2]; st[2] = st[14]; st[14] = t;
  t = st[5]; st[5] = st[9];  st[9]  = t;
  t = st[6]; st[6] = st[10]; st[10] = t;
  // RY(w[k]) on wires 0..3 (bit 3-k)
  #pragma unroll
  for (int k = 0; k < 4; ++k) {
    float a5 = 0.5f * w[k];
    float c = __cosf(a5), s = __sinf(a5);
    const int m = 8 >> k;
    #pragma unroll
    for (int i = 0; i < 16; ++i) {
      if (!(i & m)) {
        cplx a = st[i], bb = st[i|m];
        st[i].re   = c*a.re - s*bb.re;  st[i].im   = c*a.im - s*bb.im;
        st[i|m].re = s*a.re + c*bb.re;  st[i|m].im = s*a.im + c*bb.im;
      }
    }
  }
  // P2: i ^= 0x3 iff parity(i&0xC): swap pairs (4,7),(5,6),(8,11),(9,10)
  t = st[4]; st[4] = st[7];  st[7]  = t;
  t = st[5]; st[5] = st[6];  st[6]  = t;
  t = st[8]; st[8] = st[11]; st[11] = t;
  t = st[9]; st[9] = st[10]; st[10] = t;

  float z2 = 0.f, z3 = 0.f;
  #pragma unroll
  for (int i = 0; i < 16; ++i) {
    float p = st[i].re*st[i].re + st[i].im*st[i].im;
    z2 += ((i>>1)&1) ? -p : p;   // wire 2 = bit 1
    z3 += ( i    &1) ? -p : p;   // wire 3 = bit 0
  }
  *z_w2 = z2; *z_w3 = z3;
}

__global__ __launch_bounds__(256)
void qae_kernel(const float* __restrict__ x,
                const float* __restrict__ met_w,
                const float* __restrict__ ele_w,
                const float* __restrict__ mu_w,
                const float* __restrict__ jet_w,
                float* __restrict__ out, int B, int jet_blocks) {
  if ((int)blockIdx.x < jet_blocks) {
    int wave = blockIdx.x * 4 + (threadIdx.x >> 6);
    int lane = threadIdx.x & 63;
    if (wave < B)
      jet_sim(x + (size_t)wave*56, jet_w, out, wave, lane, 5*B);
  } else {
    int b = (blockIdx.x - jet_blocks) * 256 + threadIdx.x;
    if (b >= B) return;
    const float* xr = x + (size_t)b*56;
    // ---- met: n=1, eta=0 ----
    {
      float pt = xr[0], phi = xr[1], mw = met_w[0];
      float cy = __cosf(0.5f*pt),  sy = __sinf(0.5f*pt);
      float cz = __cosf(0.5f*phi), sz = __sinf(0.5f*phi);
      float cw = __cosf(0.5f*mw),  sw = __sinf(0.5f*mw);
      cplx al; al.re = cz*cy; al.im = -sz*cy;   // e^{-i phi/2} * cos(pt/2)
      cplx be; be.re = cz*sy; be.im =  sz*sy;   // e^{+i phi/2} * sin(pt/2)
      cplx a0; a0.re = cw*al.re - sw*be.re; a0.im = cw*al.im - sw*be.im;
      cplx a1; a1.re = sw*al.re + cw*be.re; a1.im = sw*al.im + cw*be.im;
      out[b] = (a0.re*a0.re + a0.im*a0.im) - (a1.re*a1.re + a1.im*a1.im);
    }
    float z2, z3;
    sim4(xr+2,  xr+6,  xr+10, ele_w, &z2, &z3);
    out[B   + b*2 + 0] = z2;  out[B   + b*2 + 1] = z3;
    sim4(xr+14, xr+18, xr+22, mu_w, &z2, &z3);
    out[3*B + b*2 + 0] = z2;  out[3*B + b*2 + 1] = z3;
  }
}

extern "C" void kernel_launch(void* const* d_in, const int* in_sizes, int n_in,
                              void* d_out, int out_size, void* d_ws, size_t ws_size,
                              hipStream_t stream) {
  const float* x     = (const float*)d_in[0];
  const float* met_w = (const float*)d_in[1];
  const float* ele_w = (const float*)d_in[2];
  const float* mu_w  = (const float*)d_in[3];
  const float* jet_w = (const float*)d_in[4];
  float* out = (float*)d_out;
  int B = in_sizes[0] / 56;
  int jet_blocks   = (B * 64 + 255) / 256;   // one wave per event
  int small_blocks = (B + 255) / 256;        // one thread per event
  qae_kernel<<<dim3(jet_blocks + small_blocks), dim3(256), 0, stream>>>(
      x, met_w, ele_w, mu_w, jet_w, out, B, jet_blocks);
}